// Round 5
// baseline (4436.449 us; speedup 1.0000x reference)
//
#include <hip/hip_runtime.h>
#include <hip/hip_fp16.h>

// SoftRR: n=1024, m=8192, rounds=8, TAU=1.0
//   scan over 8192 rows (V tiled x8):
//     y = softmax((row - min(row) + 1) * c);  c = (1-y)*c
//   pi[i][j] = sum over rounds of y
//
// R9: barrier-free dataflow scan. Two-point fit of R4/R6/R8 counters:
// step = F + X with F ~= 1000 cy FIXED (16-wave lockstep barrier + LDS round
// trip + synchronized post-barrier stall) and X ~= 400 cy issue. R5/R7/R8
// attacked X and moved nothing; R9 attacks F:
//   - s_barrier ELIMINATED. Cross-wave reduce via a ring of 4x16 seq-tagged
//     8-byte LDS slots. Producer lane63 publishes (partial, tag=s+2) as ONE
//     8-B relaxed atomic store (tag+value travel together: no fences, no
//     torn flags). Consumers poll (tag==s+1) with 8-B atomic loads, then the
//     same 4-level dpp reduce. Waves decouple; max skew = 1 step < ring 4
//     (a wave cannot pass step s without all waves' step-s partials).
//   - base otherwise identical to R6 (best measured): f16 A, scalar fma_mix
//     math, 16 waves x 8 cols, prefetch 3 ahead, store-only R + sum8.

#define N_ROWS 1024
#define M_COLS 8192
#define STEPS  8192
#define LOG2E  1.4426950408889634f

using half8  = __attribute__((ext_vector_type(8))) _Float16;
using half2v = __attribute__((ext_vector_type(2))) _Float16;

__device__ __forceinline__ float fast_exp2(float x) {
#if __has_builtin(__builtin_amdgcn_exp2f)
  return __builtin_amdgcn_exp2f(x);
#else
  return exp2f(x);
#endif
}
__device__ __forceinline__ float fast_rcp(float x) {
#if __has_builtin(__builtin_amdgcn_rcpf)
  return __builtin_amdgcn_rcpf(x);
#else
  return 1.0f / x;
#endif
}
__device__ __forceinline__ unsigned pack_f16_u32(float y0, float y1) {
  return __builtin_bit_cast(unsigned, __builtin_amdgcn_cvt_pkrtz(y0, y1));
}

template <int CTRL>
__device__ __forceinline__ float dpp_add(float x) {
  int yi = __builtin_amdgcn_update_dpp(0, __builtin_bit_cast(int, x),
                                       CTRL, 0xf, 0xf, true);
  return x + __builtin_bit_cast(float, yi);
}

// full 64-lane sum; result valid in lane 63
__device__ __forceinline__ float wave_sum_to_lane63(float x) {
  x = dpp_add<0x111>(x);  // row_shr:1
  x = dpp_add<0x112>(x);  // row_shr:2
  x = dpp_add<0x114>(x);  // row_shr:4
  x = dpp_add<0x118>(x);  // row_shr:8   -> lane15 of each row = row sum
  x = dpp_add<0x142>(x);  // row_bcast15
  x = dpp_add<0x143>(x);  // row_bcast31 -> lane63 = total
  return x;
}

// ---------------- rowmin: one block per row ----------------
__global__ void softrr_rowmin(const float* __restrict__ V, float* __restrict__ rmin) {
  const int row = blockIdx.x;
  const float* p = V + (size_t)row * M_COLS;
  float m = 1e30f;
  for (int j = threadIdx.x; j < M_COLS; j += 256) m = fminf(m, p[j]);
#pragma unroll
  for (int off = 32; off; off >>= 1) m = fminf(m, __shfl_xor(m, off, 64));
  __shared__ float sm[4];
  if ((threadIdx.x & 63) == 0) sm[threadIdx.x >> 6] = m;
  __syncthreads();
  if (threadIdx.x == 0) {
    rmin[row] = fminf(fminf(sm[0], sm[1]), fminf(sm[2], sm[3]));
  }
}

// ---------------- prep (f16): a = (V - rowmin + 1) * log2e ----------------
__global__ void softrr_prep16(const float* __restrict__ V, const float* __restrict__ rmin,
                              __half* __restrict__ A) {
  const int idx8 = blockIdx.x * 256 + threadIdx.x;   // 1M half8 groups
  const int row = idx8 >> 10;                        // 1024 half8 per row
  const float mn = rmin[row];
  const float4* v4 = (const float4*)V;
  float4 va = v4[2 * idx8];
  float4 vb = v4[2 * idx8 + 1];
  half8 o;
  o[0] = (_Float16)((va.x - mn + 1.0f) * LOG2E);
  o[1] = (_Float16)((va.y - mn + 1.0f) * LOG2E);
  o[2] = (_Float16)((va.z - mn + 1.0f) * LOG2E);
  o[3] = (_Float16)((va.w - mn + 1.0f) * LOG2E);
  o[4] = (_Float16)((vb.x - mn + 1.0f) * LOG2E);
  o[5] = (_Float16)((vb.y - mn + 1.0f) * LOG2E);
  o[6] = (_Float16)((vb.z - mn + 1.0f) * LOG2E);
  o[7] = (_Float16)((vb.w - mn + 1.0f) * LOG2E);
  ((half8*)A)[idx8] = o;
}

// ---------------- R9 dataflow step body ----------------
// Ring protocol: partials of e_s live in ring[s&3] with tag s+1 (published
// at the tail of step s-1 / the prologue). Step s (POS = s&3 compile-time):
//   window: store y_{s-1}, prefetch A(s+3)            (independent of S_s)
//   poll ring[POS] for tag s+1 -> 16 partials -> dpp4 -> S_s -> Sinv
//   y = e*Sinv; c' = fma(-y,c,c); e' = exp2(fma_mix(a_{s+1}, c'))
//   wave_sum -> lane63 publishes (partial(e_{s+1}), s+2) into ring[(POS+1)&3]
//   pack y -> o (off critical path)
template <int POS>
__device__ __forceinline__ void rr_step_df(
    int s,
    const half8& acur, half8& adst,
    float (&e)[8], float (&c)[8], uint4& o,
    const half8* __restrict__ A8, uint4* __restrict__ R4,
    unsigned long long (*ring)[16], int t, int lane, int wavei)
{
  // ---- window: independent of S_s ----
  R4[(size_t)((s - 1) & (STEPS - 1)) * 1024 + t] = o;      // y_{s-1}
  adst = A8[((s + 3) & (N_ROWS - 1)) * 1024 + t];          // prefetch A

  // ---- poll partials of e_s (tag s+1) ----
  const unsigned want = (unsigned)(s + 1);
  unsigned long long v;
  do {
    v = __hip_atomic_load(&ring[POS][lane & 15], __ATOMIC_RELAXED,
                          __HIP_MEMORY_SCOPE_WORKGROUP);
  } while ((unsigned)(v >> 32) != want);
  float x = __uint_as_float((unsigned)v);

  // reduce the 16 slot values (each 16-lane dpp row holds all 16)
  x = dpp_add<0x111>(x);
  x = dpp_add<0x112>(x);
  x = dpp_add<0x114>(x);
  x = dpp_add<0x118>(x);   // lane15 = total
  const float S = __builtin_bit_cast(
      float, __builtin_amdgcn_readlane(__builtin_bit_cast(int, x), 15));
  const float Sinv = fast_rcp(S);

  // ---- chain: y = e*Sinv; c' = c - y*c; e' = exp2(a*c') ----
  float y[8];
#pragma unroll
  for (int k = 0; k < 8; ++k) {
    y[k] = e[k] * Sinv;
    c[k] = __builtin_fmaf(-y[k], c[k], c[k]);
    e[k] = fast_exp2(__builtin_fmaf((float)acur[k], c[k], 0.0f));  // v_fma_mix
  }
  float l = ((e[0] + e[1]) + (e[2] + e[3])) + ((e[4] + e[5]) + (e[6] + e[7]));
  l = wave_sum_to_lane63(l);
  if (lane == 63) {
    const unsigned long long pv =
        ((unsigned long long)(unsigned)(s + 2) << 32) |
        (unsigned long long)__builtin_bit_cast(unsigned, l);
    __hip_atomic_store(&ring[(POS + 1) & 3][wavei], pv, __ATOMIC_RELAXED,
                       __HIP_MEMORY_SCOPE_WORKGROUP);
  }

  // ---- tail (off critical path): pack y_s for next-step store ----
  o.x = pack_f16_u32(y[0], y[1]);
  o.y = pack_f16_u32(y[2], y[3]);
  o.z = pack_f16_u32(y[4], y[5]);
  o.w = pack_f16_u32(y[6], y[7]);
}

// ---------------- main scan (R9): 1024 thr (16 waves), 8 cols/thread --------
__global__ void __launch_bounds__(1024) softrr_scan_df(const __half* __restrict__ Ah,
                                                       __half* __restrict__ Rh) {
  const int t = threadIdx.x;          // 0..1023, owns cols 8t..8t+7
  const int wavei = t >> 6;           // 0..15
  const int lane = t & 63;
  __shared__ unsigned long long ring[4][16];   // (tag<<32)|f32bits(partial)

  const half8* __restrict__ A8 = (const half8*)Ah;
  uint4* __restrict__ R4 = (uint4*)Rh;

  // zero all tags; single barrier of the whole kernel
  if (t < 64) ring[t >> 4][t & 15] = 0ULL;
  __syncthreads();

  float c[8], e[8];
#pragma unroll
  for (int k = 0; k < 8; ++k) c[k] = 1.0f;

  // prologue: row0 -> e_0; rows 1,2 into the A ring
  half8 r0 = A8[t];
  half8 pA = A8[1024 + t];    // row 1
  half8 pB = A8[2048 + t];    // row 2
  half8 pC, pD;

#pragma unroll
  for (int k = 0; k < 8; ++k) e[k] = fast_exp2((float)r0[k]);   // c_0 = 1
  {
    float l = ((e[0] + e[1]) + (e[2] + e[3])) + ((e[4] + e[5]) + (e[6] + e[7]));
    l = wave_sum_to_lane63(l);
    if (lane == 63) {
      const unsigned long long pv =
          (1ULL << 32) | (unsigned long long)__builtin_bit_cast(unsigned, l);
      __hip_atomic_store(&ring[0][wavei], pv, __ATOMIC_RELAXED,
                         __HIP_MEMORY_SCOPE_WORKGROUP);
    }
  }
  uint4 o = make_uint4(0u, 0u, 0u, 0u);  // garbage y_{-1}; only hits row 8191

  // x4 unroll: A-buffer cycle period 4, ring index compile-time
  for (int s = 0; s < STEPS; s += 4) {
    rr_step_df<0>(s + 0, pA, pC, e, c, o, A8, R4, ring, t, lane, wavei);
    rr_step_df<1>(s + 1, pB, pD, e, c, o, A8, R4, ring, t, lane, wavei);
    rr_step_df<2>(s + 2, pC, pA, e, c, o, A8, R4, ring, t, lane, wavei);
    rr_step_df<3>(s + 3, pD, pB, e, c, o, A8, R4, ring, t, lane, wavei);
  }

  // flush y_{8191} (packed in o; also overwrites the s=0 garbage row)
  R4[(size_t)(STEPS - 1) * 1024 + t] = o;
}

// ---------------- epilogue: out[i][j] = sum_r R[r*1024+i][j] (f32) ----------------
__global__ void softrr_sum8(const __half* __restrict__ Rh, float* __restrict__ out) {
  const int idx8 = blockIdx.x * 256 + threadIdx.x;   // 1M half8 outputs
  const half8* R8 = (const half8*)Rh;
  float acc[8];
  {
    half8 v = R8[idx8];
#pragma unroll
    for (int k = 0; k < 8; ++k) acc[k] = (float)v[k];
  }
#pragma unroll
  for (int r = 1; r < 8; ++r) {
    half8 v = R8[(size_t)r * 1024 * 1024 + idx8];
#pragma unroll
    for (int k = 0; k < 8; ++k) acc[k] += (float)v[k];
  }
  ((float4*)out)[2 * idx8]     = make_float4(acc[0], acc[1], acc[2], acc[3]);
  ((float4*)out)[2 * idx8 + 1] = make_float4(acc[4], acc[5], acc[6], acc[7]);
}

// ---------------- fallback B: f32 direct (tiny ws) ----------------
__global__ void __launch_bounds__(1024) softrr_scan_b(const float* __restrict__ V,
                                                      const float* __restrict__ rmin,
                                                      float* __restrict__ out) {
  const int t = threadIdx.x;
  const int wave = t >> 6;
  const int lane = t & 63;
  __shared__ float partials[2][16];
  __shared__ float smin[N_ROWS];
  smin[t] = rmin[t];
  __syncthreads();
  const float4* __restrict__ V4 = (const float4*)V;
  float4* O4 = (float4*)out;
  float c[8];
#pragma unroll
  for (int k = 0; k < 8; ++k) c[k] = 1.0f;
  float4 va = V4[2 * t], vb = V4[2 * t + 1];
  float4 pa, pb;
  for (int s = 0; s < STEPS; ++s) {
    const int i = s & (N_ROWS - 1);
    const int r = s >> 10;
    const int in_ = (s + 1) & (N_ROWS - 1);
    float4 van = V4[in_ * 2048 + 2 * t];
    float4 vbn = V4[in_ * 2048 + 2 * t + 1];
    const float mn = smin[i];
    const float base = (1.0f - mn) * LOG2E;
    float vv[8] = {va.x, va.y, va.z, va.w, vb.x, vb.y, vb.z, vb.w};
    float e[8];
    float l = 0.0f;
#pragma unroll
    for (int k = 0; k < 8; ++k) {
      float zb = __builtin_fmaf(vv[k], LOG2E, base);
      e[k] = fast_exp2(zb * c[k]);
      l += e[k];
    }
#pragma unroll
    for (int off = 32; off; off >>= 1) l += __shfl_xor(l, off, 64);
    if (lane == 0) partials[s & 1][wave] = l;
    __syncthreads();
    float S = 0.0f;
#pragma unroll
    for (int w = 0; w < 16; ++w) S += partials[s & 1][w];
    const float Sinv = fast_rcp(S);
    float po[8] = {pa.x, pa.y, pa.z, pa.w, pb.x, pb.y, pb.z, pb.w};
    float o[8];
#pragma unroll
    for (int k = 0; k < 8; ++k) {
      float y = e[k] * Sinv;
      c[k] = __builtin_fmaf(-y, c[k], c[k]);
      o[k] = (r > 0) ? (po[k] + y) : y;
    }
    O4[i * 2048 + 2 * t]     = make_float4(o[0], o[1], o[2], o[3]);
    O4[i * 2048 + 2 * t + 1] = make_float4(o[4], o[5], o[6], o[7]);
    va = van; vb = vbn;
    pa = O4[in_ * 2048 + 2 * t];
    pb = O4[in_ * 2048 + 2 * t + 1];
  }
}

extern "C" void kernel_launch(void* const* d_in, const int* in_sizes, int n_in,
                              void* d_out, int out_size, void* d_ws, size_t ws_size,
                              hipStream_t stream) {
  const float* V = (const float*)d_in[0];
  float* out = (float*)d_out;
  float* rmin = (float*)d_ws;

  const size_t A16_BYTES = (size_t)N_ROWS * M_COLS * 2;        // 16 MiB
  const size_t R_BYTES   = (size_t)STEPS * M_COLS * 2;         // 128 MiB
  const size_t need_df   = 4096 + A16_BYTES + R_BYTES;         // ~144 MiB

  if (ws_size >= need_df) {
    __half* A = (__half*)((char*)d_ws + 4096);
    __half* R = (__half*)((char*)d_ws + 4096 + A16_BYTES);
    softrr_rowmin<<<N_ROWS, 256, 0, stream>>>(V, rmin);
    softrr_prep16<<<4096, 256, 0, stream>>>(V, rmin, A);
    softrr_scan_df<<<1, 1024, 0, stream>>>(A, R);
    softrr_sum8<<<4096, 256, 0, stream>>>(R, out);
  } else {
    softrr_rowmin<<<N_ROWS, 256, 0, stream>>>(V, rmin);
    softrr_scan_b<<<1, 1024, 0, stream>>>(V, rmin, out);
  }
}